// Round 8
// baseline (188.930 us; speedup 1.0000x reference)
//
#include <hip/hip_runtime.h>

#define NN 20000
#define KNEI 32
#define DIM 256
#define NHEAD 8
#define HDIM 32
#define DFFN 1024
#define QKVD 768

typedef __attribute__((ext_vector_type(8))) __bf16 bf16x8;
typedef __attribute__((ext_vector_type(8))) unsigned short u16x8;
typedef __attribute__((ext_vector_type(4))) unsigned short u16x4;
typedef __attribute__((ext_vector_type(4))) float f32x4;
typedef __attribute__((ext_vector_type(2))) float f32x2;

static __device__ __forceinline__ float b2f(unsigned short u) {
    return __builtin_bit_cast(float, (unsigned)u << 16);
}
static __device__ __forceinline__ float blo(unsigned w) {   // low bf16 of packed pair
    return __builtin_bit_cast(float, w << 16);
}
static __device__ __forceinline__ float bhi(unsigned w) {   // high bf16 of packed pair
    return __builtin_bit_cast(float, w & 0xffff0000u);
}
static __device__ __forceinline__ unsigned short f2b(float f) {
    unsigned u = __builtin_bit_cast(unsigned, f);
    return (unsigned short)((u + 0x7fff + ((u >> 16) & 1)) >> 16);
}

// ---- fp8 e4m3fn encode/decode (HW builtins on device; pure-bit-ops fallback
// so the HOST compile pass can always parse this file) ----
static __device__ __forceinline__ unsigned char fp8enc(float v) {
#if defined(__HIP_DEVICE_COMPILE__) && __has_builtin(__builtin_amdgcn_cvt_pk_fp8_f32)
    return (unsigned char)(__builtin_amdgcn_cvt_pk_fp8_f32(v, v, 0u, false) & 0xffu);
#else
    unsigned u = __builtin_bit_cast(unsigned, v);
    unsigned s = u >> 31;
    unsigned a = u & 0x7fffffffu;
    if (a >= 0x43e00000u) return (unsigned char)((s << 7) | 0x7e);  // clamp to 448
    float af = __builtin_bit_cast(float, a);
    if (af < 0.015625f) {                       // subnormal: step 2^-9
        unsigned r = (unsigned)(af * 512.0f + 0.5f);
        if (r >= 8u) return (unsigned char)((s << 7) | 0x08);
        return (unsigned char)((s << 7) | r);
    }
    unsigned lsb = (a >> 20) & 1u;              // RNE to 3 mantissa bits
    a += 0x7ffffu + lsb;
    unsigned e = (a >> 23) - 120u;
    unsigned m = (a >> 20) & 7u;
    unsigned code = (e << 3) | m;
    if (code > 0x7eu) code = 0x7eu;
    return (unsigned char)((s << 7) | code);
#endif
}

template<int SEL>
static __device__ __forceinline__ float fp8dec(unsigned word) {
#if defined(__HIP_DEVICE_COMPILE__) && __has_builtin(__builtin_amdgcn_cvt_f32_fp8)
    return __builtin_amdgcn_cvt_f32_fp8(word, SEL);
#else
    unsigned b = (word >> (SEL * 8)) & 0xffu;
    unsigned s = (b >> 7) & 1u;
    unsigned e = (b >> 3) & 0xfu;
    unsigned m = b & 7u;
    float v;
    if (e == 0) v = (float)m * 0.001953125f;    // m * 2^-9
    else        v = __builtin_bit_cast(float, ((e + 120u) << 23) | (m << 20));
    return s ? -v : v;
#endif
}

// paired fp8 decode: bytes (0,1) for HI=false, (2,3) for HI=true
template<bool HI>
static __device__ __forceinline__ f32x2 fp8pk(unsigned word) {
#if defined(__HIP_DEVICE_COMPILE__) && __has_builtin(__builtin_amdgcn_cvt_pk_f32_fp8)
    return __builtin_amdgcn_cvt_pk_f32_fp8((int)word, HI);
#else
    f32x2 r;
    r.x = fp8dec<HI ? 2 : 0>(word);
    r.y = fp8dec<HI ? 3 : 1>(word);
    return r;
#endif
}

#define GLD16(src, dst)                                                          \
    __builtin_amdgcn_global_load_lds(                                            \
        (const __attribute__((address_space(1))) void*)(const void*)(src),       \
        (__attribute__((address_space(3))) void*)(void*)(dst), 16, 0, 0)

// ---------------- bf16 MFMA GEMM, 2-phase double-buffered staging ----------------
// C[M,N] = A[M,K] @ Bt[N,K]^T + bias.
// SPLIT: Q cols (<256) -> bf16 Cb, K/V cols -> fp8 kvb rows [k(256)|v(256)]
template<int BM, int RELU, int WF32, int WBF16, int SPLIT>
__global__ __launch_bounds__(256) void gemm_mfma(const unsigned short* __restrict__ A,
                                                 const unsigned short* __restrict__ Bt,
                                                 const float* __restrict__ bias,
                                                 float* __restrict__ Cf,
                                                 unsigned short* __restrict__ Cb,
                                                 unsigned char* __restrict__ kvb,
                                                 int M, int N, int K)
{
    constexpr int BN = 128, BK = 32;
    constexpr int MI = BM / 32;
    constexpr int NI = BN / 32;

    __shared__ unsigned short As[2][BM * BK];
    __shared__ unsigned short Bs[2][BN * BK];

    const int tid  = threadIdx.x;
    const int wid  = tid >> 6;
    const int lane = tid & 63;
    const int bm = blockIdx.x * BM;
    const int bn = blockIdx.y * BN;
    const int wr = (wid >> 1) * (BM / 2);
    const int wc = (wid & 1) * (BN / 2);
    const int r0   = lane & 15;
    const int kblk = (lane >> 4) * 8;

    // staging coordinates (fixed per thread)
    int arow = bm + (tid >> 2);                 // A chunk row for t=0 (BM=64 case uses only this)
    const int aoff = (tid & 3) * 8;

    auto stage = [&](int buf, int k0) {
        #pragma unroll
        for (int t = 0; t < (BM * 4) / 256; ++t) {
            int row = bm + ((t * 256 + tid) >> 2);
            if (row >= M) row = M - 1;
            GLD16(A + (size_t)row * K + k0 + aoff,
                  &As[buf][(t * 256 + wid * 64) * 8]);
        }
        #pragma unroll
        for (int t = 0; t < (BN * 4) / 256; ++t) {
            int c = t * 256 + tid;
            GLD16(Bt + (size_t)(bn + (c >> 2)) * K + k0 + (c & 3) * 8,
                  &Bs[buf][(t * 256 + wid * 64) * 8]);
        }
    };
    (void)arow;

    f32x4 acc[MI][NI];
    #pragma unroll
    for (int i = 0; i < MI; ++i)
        #pragma unroll
        for (int j = 0; j < NI; ++j)
            acc[i][j] = (f32x4){0.f, 0.f, 0.f, 0.f};

    stage(0, 0);
    __syncthreads();                 // drain vmcnt(0): buf0 ready

    int cur = 0;
    for (int k0 = 0; k0 < K; k0 += BK) {
        if (k0 + BK < K) stage(cur ^ 1, k0 + BK);   // issue next-tile loads FIRST

        bf16x8 af[MI], bfr[NI];
        #pragma unroll
        for (int mi = 0; mi < MI; ++mi)
            af[mi] = __builtin_bit_cast(bf16x8,
                     *(const u16x8*)&As[cur][(wr + mi * 16 + r0) * BK + kblk]);
        #pragma unroll
        for (int ni = 0; ni < NI; ++ni)
            bfr[ni] = __builtin_bit_cast(bf16x8,
                     *(const u16x8*)&Bs[cur][(wc + ni * 16 + r0) * BK + kblk]);
        #pragma unroll
        for (int mi = 0; mi < MI; ++mi)
            #pragma unroll
            for (int ni = 0; ni < NI; ++ni)
                acc[mi][ni] = __builtin_amdgcn_mfma_f32_16x16x32_bf16(
                    af[mi], bfr[ni], acc[mi][ni], 0, 0, 0);

        __syncthreads();             // drain: next buf staged, cur reads consumed
        cur ^= 1;
    }

    const int r4 = (lane >> 4) * 4;
    #pragma unroll
    for (int mi = 0; mi < MI; ++mi)
        #pragma unroll
        for (int ni = 0; ni < NI; ++ni) {
            const int col = bn + wc + ni * 16 + r0;
            const float bb = bias[col];
            #pragma unroll
            for (int r = 0; r < 4; ++r) {
                const int row = bm + wr + mi * 16 + r4 + r;
                if (row < M) {
                    float v = acc[mi][ni][r] + bb;
                    if (RELU) v = fmaxf(v, 0.f);
                    if (SPLIT) {
                        if (col < 256) Cb[(size_t)row * DIM + col] = f2b(v);
                        else kvb[(size_t)row * 512 + (col - 256)] = fp8enc(v);
                    } else {
                        if (WF32)  Cf[(size_t)row * N + col] = v;
                        if (WBF16) Cb[(size_t)row * N + col] = f2b(v);
                    }
                }
            }
        }
}

// ---------------- attention v2: 2 nodes per block, lane = (head-sub, neighbor) ----------------
__global__ __launch_bounds__(512) void attn_f8(const unsigned short* __restrict__ q,
                                               const unsigned char* __restrict__ kv,
                                               const int* __restrict__ samp,
                                               unsigned short* __restrict__ o)
{
    const int n = blockIdx.x * 2 + (threadIdx.x >> 8);
    const int tid = threadIdx.x & 255;
    const int wid = tid >> 6;
    const int lane = tid & 63;
    const int j = lane & 31;
    const int hs = lane >> 5;
    const int h = wid * 2 + hs;

    const int kidx = samp[n * KNEI + j];    // lanes j and 32+j both hold kidx_j

    // q for head h: 32 bf16 dims = 16 packed pairs (same addr across j-lanes)
    const uint4* qp = (const uint4*)(q + (size_t)n * DIM + h * HDIM);
    const uint4 qa = qp[0], qb = qp[1], qc = qp[2], qd = qp[3];
    const unsigned qw[16] = {qa.x, qa.y, qa.z, qa.w, qb.x, qb.y, qb.z, qb.w,
                             qc.x, qc.y, qc.z, qc.w, qd.x, qd.y, qd.z, qd.w};

    // k row slice for (neighbor j, head h): 32 fp8 bytes
    const unsigned char* krow = kv + (size_t)kidx * 512 + h * HDIM;
    const uint4 k0 = *(const uint4*)krow;
    const uint4 k1 = *(const uint4*)(krow + 16);
    const unsigned kw[8] = {k0.x, k0.y, k0.z, k0.w, k1.x, k1.y, k1.z, k1.w};

    float s = 0.f;
    #pragma unroll
    for (int i = 0; i < 8; ++i) {           // word i = dims 4i..4i+3
        f32x2 ka = fp8pk<false>(kw[i]);
        f32x2 kb = fp8pk<true>(kw[i]);
        unsigned q0 = qw[2 * i], q1 = qw[2 * i + 1];
        s = fmaf(blo(q0), ka.x, s);
        s = fmaf(bhi(q0), ka.y, s);
        s = fmaf(blo(q1), kb.x, s);
        s = fmaf(bhi(q1), kb.y, s);
    }
    s *= 0.17677669529663687f;              // 1/sqrt(32)

    // softmax over j within each 32-lane head group
    float m = s;
    #pragma unroll
    for (int sh = 16; sh; sh >>= 1) m = fmaxf(m, __shfl_xor(m, sh));
    float e = __expf(s - m);
    float sum = e;
    #pragma unroll
    for (int sh = 16; sh; sh >>= 1) sum += __shfl_xor(sum, sh);
    const float p = __fdividef(e, sum);

    // ---- PV: lane reinterpreted as (hs, d) ----
    const int d = j;                        // dim 0..31
    const int pbits = __builtin_bit_cast(int, p);
    const int pbase = hs * 128;             // byte addr of this head's p group
    const int voff = 256 + h * HDIM + d;    // v-slice offset within kv row
    float acc = 0.f;
    #pragma unroll
    for (int jj = 0; jj < KNEI; ++jj) {
        const int kj = __builtin_amdgcn_readlane(kidx, jj);       // SGPR
        const float pj = __builtin_bit_cast(float,
            __builtin_amdgcn_ds_bpermute(pbase + jj * 4, pbits)); // imm-offset pull
        const unsigned char* vp = kv + (size_t)kj * 512 + voff;
        acc = fmaf(pj, fp8dec<0>((unsigned)*vp), acc);
    }
    o[(size_t)n * DIM + h * HDIM + d] = f2b(acc);
}

// ---------------- fused residual add + LayerNorm ----------------
// XF32: residual input fp32 (else bf16). WFOUT: write fp32 out (else bf16 out).
template<int XF32, int WFOUT>
__global__ __launch_bounds__(256) void add_ln(const float* __restrict__ xf,
                                              const unsigned short* __restrict__ xb,
                                              const unsigned short* __restrict__ y,
                                              const float* __restrict__ gamma,
                                              const float* __restrict__ beta,
                                              float* __restrict__ outf,
                                              unsigned short* __restrict__ outb, int M)
{
    const int row = blockIdx.x * 4 + (threadIdx.x >> 6);
    const int lane = threadIdx.x & 63;
    if (row >= M) return;

    float s0, s1, s2, s3;
    if (XF32) {
        const float4 xv = *(const float4*)(xf + (size_t)row * DIM + lane * 4);
        s0 = xv.x; s1 = xv.y; s2 = xv.z; s3 = xv.w;
    } else {
        const u16x4 xv = *(const u16x4*)(xb + (size_t)row * DIM + lane * 4);
        s0 = b2f(xv[0]); s1 = b2f(xv[1]); s2 = b2f(xv[2]); s3 = b2f(xv[3]);
    }
    const u16x4 yv = *(const u16x4*)(y + (size_t)row * DIM + lane * 4);
    s0 += b2f(yv[0]); s1 += b2f(yv[1]); s2 += b2f(yv[2]); s3 += b2f(yv[3]);

    float sum = s0 + s1 + s2 + s3;
    float sq = s0 * s0 + s1 * s1 + s2 * s2 + s3 * s3;
    #pragma unroll
    for (int sh = 32; sh; sh >>= 1) {
        sum += __shfl_xor(sum, sh);
        sq  += __shfl_xor(sq, sh);
    }
    float mean = sum * (1.f / 256.f);
    float var = sq * (1.f / 256.f) - mean * mean;
    float rstd = rsqrtf(var + 1e-5f);

    const float4 gv = *(const float4*)(gamma + lane * 4);
    const float4 bv = *(const float4*)(beta + lane * 4);
    float o0 = (s0 - mean) * rstd * gv.x + bv.x;
    float o1 = (s1 - mean) * rstd * gv.y + bv.y;
    float o2 = (s2 - mean) * rstd * gv.z + bv.z;
    float o3 = (s3 - mean) * rstd * gv.w + bv.w;
    if (WFOUT) {
        float4 ov = { o0, o1, o2, o3 };
        *(float4*)(outf + (size_t)row * DIM + lane * 4) = ov;
    } else {
        u16x4 bb = { f2b(o0), f2b(o1), f2b(o2), f2b(o3) };
        *(u16x4*)(outb + (size_t)row * DIM + lane * 4) = bb;
    }
}

// ---------------- conversions ----------------
__global__ __launch_bounds__(256) void cvt_bf16(const float* __restrict__ in,
                                                unsigned short* __restrict__ out, int n4)
{
    int i = blockIdx.x * 256 + threadIdx.x;
    if (i < n4) {
        float4 v = ((const float4*)in)[i];
        u16x4 b = { f2b(v.x), f2b(v.y), f2b(v.z), f2b(v.w) };
        ((u16x4*)out)[i] = b;
    }
}

__global__ __launch_bounds__(256) void cvt_transpose(const float* __restrict__ W,
                                                     unsigned short* __restrict__ Wt,
                                                     int K, int N)
{
    __shared__ float t[32][33];
    const int n0 = blockIdx.x * 32, k0 = blockIdx.y * 32;
    const int tx = threadIdx.x & 31, ty = threadIdx.x >> 5;
    #pragma unroll
    for (int i = 0; i < 32; i += 8)
        t[ty + i][tx] = W[(size_t)(k0 + ty + i) * N + n0 + tx];
    __syncthreads();
    #pragma unroll
    for (int i = 0; i < 32; i += 8)
        Wt[(size_t)(n0 + ty + i) * K + k0 + tx] = f2b(t[tx][ty + i]);
}

// four 256x256 weights in one launch (blockIdx.z selects)
__global__ __launch_bounds__(256) void cvt_transpose4(const float* __restrict__ Wa,
                                                      const float* __restrict__ Wb,
                                                      const float* __restrict__ Wc,
                                                      const float* __restrict__ Wd,
                                                      unsigned short* __restrict__ Ta,
                                                      unsigned short* __restrict__ Tb,
                                                      unsigned short* __restrict__ Tc,
                                                      unsigned short* __restrict__ Td)
{
    const float* W; unsigned short* T;
    switch (blockIdx.z) {
        case 0:  W = Wa; T = Ta; break;
        case 1:  W = Wb; T = Tb; break;
        case 2:  W = Wc; T = Tc; break;
        default: W = Wd; T = Td; break;
    }
    __shared__ float t[32][33];
    const int n0 = blockIdx.x * 32, k0 = blockIdx.y * 32;
    const int tx = threadIdx.x & 31, ty = threadIdx.x >> 5;
    #pragma unroll
    for (int i = 0; i < 32; i += 8)
        t[ty + i][tx] = W[(size_t)(k0 + ty + i) * DIM + n0 + tx];
    __syncthreads();
    #pragma unroll
    for (int i = 0; i < 32; i += 8)
        T[(size_t)(n0 + ty + i) * DIM + k0 + tx] = f2b(t[tx][ty + i]);
}

__global__ void concat_bias(const float* a, const float* b, const float* c, float* out)
{
    int i = blockIdx.x * 256 + threadIdx.x;
    if (i < 256) out[i] = a[i];
    else if (i < 512) out[i] = b[i - 256];
    else if (i < 768) out[i] = c[i - 512];
}

extern "C" void kernel_launch(void* const* d_in, const int* in_sizes, int n_in,
                              void* d_out, int out_size, void* d_ws, size_t ws_size,
                              hipStream_t stream)
{
    const float* x    = (const float*)d_in[0];
    const int*   samp = (const int*)  d_in[1];
    const float* Wq = (const float*)d_in[2];  const float* bq = (const float*)d_in[3];
    const float* Wk = (const float*)d_in[4];  const float* bk = (const float*)d_in[5];
    const float* Wv = (const float*)d_in[6];  const float* bv = (const float*)d_in[7];
    const float* Wo = (const float*)d_in[8];  const float* bo = (const float*)d_in[9];
    const float* W1 = (const float*)d_in[10]; const float* b1 = (const float*)d_in[11];
    const float* W2 = (const float*)d_in[12]; const float* b2 = (const float*)d_in[13];
    const float* g1 = (const float*)d_in[14]; const float* be1 = (const float*)d_in[15];
    const float* g2 = (const float*)d_in[16]; const float* be2 = (const float*)d_in[17];
    float* out = (float*)d_out;

    char* w = (char*)d_ws;
    const size_t MB = 1u << 20;
    // weights (live whole launch): 0 .. 2 MB
    unsigned short* WqkvT = (unsigned short*)(w + 0);          // [768][256] bf16
    unsigned short* WoT   = (unsigned short*)(w + 393216);     // [256][256]
    unsigned short* W1T   = (unsigned short*)(w + 524288);     // [1024][256]
    unsigned short* W2T   = (unsigned short*)(w + 1048576);    // [256][1024]
    float*          bqkv  = (float*)(w + 1572864);             // [768]
    // activations — NON-OVERLAPPING liveness map:
    //   xb/ob  2..12.24MB | qb 13..23.24 | kvb 24..34.24 | attno 35..45.24
    //   x1b   46..56.24   | hmid 57..97.96
    unsigned short* xb    = (unsigned short*)(w + 2 * MB);     // [NN][256] bf16
    unsigned short* qb    = (unsigned short*)(w + 13 * MB);    // [NN][256] bf16
    unsigned char*  kvb   = (unsigned char*) (w + 24 * MB);    // [NN][512] fp8
    unsigned short* ob    = xb;                                // reuse xb (dead after QKV)
    unsigned short* attno = (unsigned short*)(w + 35 * MB);    // [NN][256] bf16
    unsigned short* x1b   = (unsigned short*)(w + 46 * MB);    // [NN][256] bf16; live to LN2
    unsigned short* hmid  = (unsigned short*)(w + 57 * MB);    // [NN][1024] bf16
    unsigned short* ffb   = attno;                             // reuse attno (dead after LN1)

    const dim3 blk(256);

    // ---- weight prep ----
    cvt_transpose4<<<dim3(8, 8, 4), blk, 0, stream>>>(
        Wq, Wk, Wv, Wo, WqkvT, WqkvT + 256 * 256, WqkvT + 512 * 256, WoT);
    cvt_transpose<<<dim3(32, 8), blk, 0, stream>>>(W1, W1T, DIM, DFFN);
    cvt_transpose<<<dim3(8, 32), blk, 0, stream>>>(W2, W2T, DFFN, DIM);
    concat_bias<<<dim3(3), blk, 0, stream>>>(bq, bk, bv, bqkv);
    cvt_bf16<<<dim3((NN * DIM / 4 + 255) / 256), blk, 0, stream>>>(x, xb, NN * DIM / 4);

    // ---- fused QKV projection: Q->bf16, K/V->fp8 ----
    gemm_mfma<128, 0, 0, 0, 1><<<dim3(157, 6), blk, 0, stream>>>(
        xb, WqkvT, bqkv, nullptr, qb, kvb, NN, QKVD, DIM);

    // ---- attention (2 nodes per block) ----
    attn_f8<<<dim3(NN / 2), dim3(512), 0, stream>>>(qb, kvb, samp, ob);

    // ---- out proj -> bf16, residual(x f32)+LN1 -> bf16 ----
    gemm_mfma<64, 0, 0, 1, 0><<<dim3(313, 2), blk, 0, stream>>>(
        ob, WoT, bo, nullptr, attno, nullptr, NN, DIM, DIM);
    add_ln<1, 0><<<dim3(NN / 4), blk, 0, stream>>>(x, nullptr, attno, g1, be1,
                                                   nullptr, x1b, NN);

    // ---- FFN ----
    gemm_mfma<128, 1, 0, 1, 0><<<dim3(157, 8), blk, 0, stream>>>(
        x1b, W1T, b1, nullptr, hmid, nullptr, NN, DFFN, DIM);
    gemm_mfma<64, 0, 0, 1, 0><<<dim3(313, 2), blk, 0, stream>>>(
        hmid, W2T, b2, nullptr, ffb, nullptr, NN, DIM, DFFN);
    add_ln<0, 1><<<dim3(NN / 4), blk, 0, stream>>>(nullptr, x1b, ffb, g2, be2,
                                                   out, nullptr, NN);
}